// Round 14
// baseline (37.887 us; speedup 1.0000x reference)
//
#include <hip/hip_runtime.h>
#include <hip/hip_bf16.h>
#include <math.h>

#define TT 2048
#define HH 512   // hidden = NUM_HEADS*DIM_KEY
#define NH 8
#define DK 64
#define WIN 16
#define NC 33    // 2*WIN+1
#define MT 8192  // B*T rows

typedef __attribute__((ext_vector_type(8))) short bf16x8;
typedef __attribute__((ext_vector_type(4))) float f32x4;

__device__ inline ushort f2bf(float f) {   // RNE float -> bf16 bits
  uint u = __builtin_bit_cast(uint, f);
  return (ushort)((u + 0x7FFFu + ((u >> 16) & 1u)) >> 16);
}
__device__ inline ushort cvt1(float f) {   // compiler cast (v_cvt_pk capable)
  __hip_bfloat16 h = __float2bfloat16(f);
  return __builtin_bit_cast(ushort, h);
}

// ============ FULLY FUSED: proj(Q,K) + windowed attn, ONE dispatch =========
// Block: 512 thr (8 waves), grid (128 row-tiles, 4 head-pairs).
// Each block projects q rows [m0,m0+64) and k rows [m0-16,m0+80) (recompute
// x1.5, removes all cross-block deps) for its 128 output cols (2 heads),
// keeps results in LDS, then runs the verified MFMA attention per wave.
// LDS phase 1 (52KB): AsQ[64x64]@0, AsK[96x64]@4096, WsQ[128x64]@10240,
// WsK[128x64]@18432 (ushort units). Phase 2 (aliased, 40KB): QP[64x128]@0,
// KP[96x128]@8192. 16B-granule XOR swizzle everywhere: stored granule =
// g ^ (row&7); reads use the same key.
__global__ __launch_bounds__(512, 2) void fused_mha(
    const float* __restrict__ qin, const float* __restrict__ kin,
    const float* __restrict__ Wq, const float* __restrict__ Wk,
    const float* __restrict__ bq, const float* __restrict__ bk,
    float* __restrict__ out)
{
  __shared__ ushort lds[26624];   // 52 KB

  const int m0 = blockIdx.x * 64;       // absolute q-row base
  const int n0 = blockIdx.y * 128;      // output col base (heads 2y, 2y+1)
  const int t  = threadIdx.x;
  const int w  = t >> 6;                // wave 0..7
  const int l  = t & 63;
  const int lr = l & 15;
  const int hi = l >> 4;
  const int swz = lr & 7;

  // ---- proj task map: tasks 0-3 = QP sub-tiles, 4-9 = KP sub-tiles ----
  const bool isQA  = (w < 4);
  const int  rowA  = (isQA ? w : w - 4) * 16;   // row base within its tile
  const int  ldsAA = isQA ? 0 : 4096;           // A-stage base (ushorts)
  const int  ldsWA = isQA ? 10240 : 18432;      // W-stage base
  const bool hasB  = (w < 2);
  const int  rowB  = (4 + w) * 16;              // KP sub-tiles 4,5

  f32x4 accA[8] = {};
  f32x4 accB[8] = {};

  // =================== phase 1: projection ===================
  for (int k0 = 0; k0 < HH; k0 += 64) {
    // ---- stage 3328 granules (8 bf16 each): 6 full rounds + 1 half ----
#pragma unroll
    for (int p = 0; p < 7; ++p) {
      const int u = p * 512 + t;
      if (p < 6 || t < 256) {
        const float* src; int base, lg;
        if (u < 512)       { lg = u;        const int r = lg >> 3; src = qin + (size_t)(m0 + r) * HH; base = 0; }
        else if (u < 1280) { lg = u - 512;  int r = lg >> 3; int ar = m0 - 16 + r;
                             ar = ar < 0 ? 0 : (ar > MT - 1 ? MT - 1 : ar);
                             src = kin + (size_t)ar * HH; base = 4096; }
        else if (u < 2304) { lg = u - 1280; const int r = lg >> 3; src = Wq + (size_t)(n0 + r) * HH; base = 10240; }
        else               { lg = u - 2304; const int r = lg >> 3; src = Wk + (size_t)(n0 + r) * HH; base = 18432; }
        const int rr = lg >> 3;
        const int g  = (lg & 7) ^ (rr & 7);
        const float* gp = src + k0 + g * 8;
        float4 x = ((const float4*)gp)[0], y = ((const float4*)gp)[1];
        union { ushort s[8]; uint4 v; } pk;
        pk.s[0]=cvt1(x.x); pk.s[1]=cvt1(x.y); pk.s[2]=cvt1(x.z); pk.s[3]=cvt1(x.w);
        pk.s[4]=cvt1(y.x); pk.s[5]=cvt1(y.y); pk.s[6]=cvt1(y.z); pk.s[7]=cvt1(y.w);
        *(uint4*)&lds[base + lg * 8] = pk.v;
      }
    }
    __syncthreads();

    // ---- compute: task A (all waves), task B (waves 0-1) ----
#pragma unroll
    for (int kk = 0; kk < 64; kk += 32) {
      const int gq = (kk >> 3) + hi;
      bf16x8 afA = *(const bf16x8*)&lds[ldsAA + (rowA + lr) * 64 + ((gq ^ swz) * 8)];
#pragma unroll
      for (int n = 0; n < 8; ++n) {
        bf16x8 bw = *(const bf16x8*)&lds[ldsWA + (n * 16 + lr) * 64 + ((gq ^ swz) * 8)];
        accA[n] = __builtin_amdgcn_mfma_f32_16x16x32_bf16(afA, bw, accA[n], 0, 0, 0);
      }
      if (hasB) {
        bf16x8 afB = *(const bf16x8*)&lds[4096 + (rowB + lr) * 64 + ((gq ^ swz) * 8)];
#pragma unroll
        for (int n = 0; n < 8; ++n) {
          bf16x8 bw = *(const bf16x8*)&lds[18432 + (n * 16 + lr) * 64 + ((gq ^ swz) * 8)];
          accB[n] = __builtin_amdgcn_mfma_f32_16x16x32_bf16(afB, bw, accB[n], 0, 0, 0);
        }
      }
    }
    __syncthreads();
  }

  // ---- epilogue 1: acc (+bias) -> QP/KP LDS (bf16, swizzled scalar) ----
  // C-frag layout (rounds 3-13 verified): row = hi*4+q, col = n*16+lr.
  {
    const float* biasA = isQA ? bq : bk;
    const int pbaseA = isQA ? 0 : 8192;
#pragma unroll
    for (int n = 0; n < 8; ++n) {
      const float bc = biasA[n0 + n * 16 + lr];
      const int c = n * 16 + lr;
#pragma unroll
      for (int q_ = 0; q_ < 4; ++q_) {
        const int row = rowA + hi * 4 + q_;
        lds[pbaseA + row * 128 + (((c >> 3) ^ (row & 7)) << 3) + (c & 7)] =
            f2bf(accA[n][q_] + bc);
      }
    }
    if (hasB) {
#pragma unroll
      for (int n = 0; n < 8; ++n) {
        const float bc = bk[n0 + n * 16 + lr];
        const int c = n * 16 + lr;
#pragma unroll
        for (int q_ = 0; q_ < 4; ++q_) {
          const int row = rowB + hi * 4 + q_;
          lds[8192 + row * 128 + (((c >> 3) ^ (row & 7)) << 3) + (c & 7)] =
              f2bf(accB[n][q_] + bc);
        }
      }
    }
  }
  __syncthreads();

  // =================== phase 2: attention (1 wave = 16 rows x 1 head) ====
  const int s  = w & 3;                 // row sub-tile 0..3
  const int hl = w >> 2;                // head-local 0/1
  const int bb = m0 >> 11;              // batch
  const int ml = m0 & (TT - 1);         // within-batch block row base
  const int i0l = ml + s * 16;          // within-batch tile row base

  int jbt = i0l - WIN;
  if (jbt < 0) jbt = 0;
  if (jbt > TT - NC) jbt = TT - NC;
  const int krb = jbt - ml + 16;        // KP LDS row of window col 0

  f32x4 acc[3] = {};
#pragma unroll
  for (int kk = 0; kk < 64; kk += 32) {
    const int gc = hl * 8 + (kk >> 3) + hi;   // col granule within 16
    const int rowq = s * 16 + lr;
    bf16x8 aq = *(const bf16x8*)&lds[rowq * 128 + (((gc) ^ (rowq & 7)) << 3)];
#pragma unroll
    for (int a = 0; a < 3; ++a) {
      const int kr = krb + a * 16 + lr;       // in [0,96)
      bf16x8 bkf = *(const bf16x8*)&lds[8192 + kr * 128 + (((gc) ^ (kr & 7)) << 3)];
      acc[a] = __builtin_amdgcn_mfma_f32_16x16x32_bf16(aq, bkf, acc[a], 0, 0, 0);
    }
  }

  float e[3][4];
  float inv[4];
#pragma unroll
  for (int q_ = 0; q_ < 4; ++q_) {
    const int i = i0l + hi * 4 + q_;
    const int j0 = jbt + lr, j1 = j0 + 16, j2 = j0 + 32;
    float s0 = (j0 >= i - WIN && j0 <= i + WIN && j0 < TT) ? acc[0][q_] * 0.125f : -INFINITY;
    float s1 = (j1 >= i - WIN && j1 <= i + WIN && j1 < TT) ? acc[1][q_] * 0.125f : -INFINITY;
    float s2 = (j2 >= i - WIN && j2 <= i + WIN && j2 < TT) ? acc[2][q_] * 0.125f : -INFINITY;
    float m = fmaxf(fmaxf(s0, s1), s2);
#pragma unroll
    for (int off = 8; off; off >>= 1) m = fmaxf(m, __shfl_xor(m, off));
    const float e0 = __expf(s0 - m);
    const float e1 = __expf(s1 - m);
    const float e2 = __expf(s2 - m);
    e[0][q_] = e0; e[1][q_] = e1; e[2][q_] = e2;
    float sum = e0 + e1 + e2;
#pragma unroll
    for (int off = 8; off; off >>= 1) sum += __shfl_xor(sum, off);
    inv[q_] = 1.0f / sum;
  }

  const int h = blockIdx.y * 2 + hl;
  const size_t obase = ((size_t)(bb * NH + h)) * TT * NC;
#pragma unroll
  for (int q_ = 0; q_ < 4; ++q_) {
    const int i = i0l + hi * 4 + q_;
    int st = i - WIN;
    if (st < 0) st = 0;
    if (st > TT - NC) st = TT - NC;
#pragma unroll
    for (int a = 0; a < 3; ++a) {
      const int c = jbt + a * 16 + lr - st;
      if (c >= 0 && c < NC)
        out[obase + (size_t)i * NC + c] = e[a][q_] * inv[q_];
    }
  }
}

extern "C" void kernel_launch(void* const* d_in, const int* in_sizes, int n_in,
                              void* d_out, int out_size, void* d_ws, size_t ws_size,
                              hipStream_t stream)
{
  const float* query = (const float*)d_in[0];
  const float* key   = (const float*)d_in[1];
  const float* Wq    = (const float*)d_in[2];
  const float* bq    = (const float*)d_in[3];
  const float* Wk    = (const float*)d_in[4];
  const float* bk    = (const float*)d_in[5];
  float* out = (float*)d_out;

  fused_mha<<<dim3(MT / 64, 4), 512, 0, stream>>>(
      query, key, Wq, Wk, bq, bk, out);
}